// Round 5
// baseline (415.365 us; speedup 1.0000x reference)
//
#include <hip/hip_runtime.h>
#include <hip/hip_bf16.h>

#define B_ 4
#define S_ 4096
#define D_ 1024
#define H_ 128

typedef unsigned short u16;
typedef unsigned int u32;
typedef short s16x8 __attribute__((ext_vector_type(8)));   // 8 bf16 (4 VGPRs)
typedef float f32x4 __attribute__((ext_vector_type(4)));   // MFMA 16x16 acc

__device__ __forceinline__ float bf2f(u16 u) { return __uint_as_float(((u32)u) << 16); }
__device__ __forceinline__ u16 f2bf(float f) {
    u32 x = __float_as_uint(f);
    u32 r = x + 0x7fffu + ((x >> 16) & 1u);   // RNE
    return (u16)(r >> 16);
}

// ---------------------------------------------------------------------------
// Kernel 0: input dtype detection (fp32 vs bf16). Verified in round 3.
// ---------------------------------------------------------------------------
__global__ void detect_dtype_kernel(const u32* __restrict__ w, int* __restrict__ flag) {
    __shared__ int smax[256];
    const int tid = threadIdx.x;
    int m = 0;
    for (int i = tid; i < 1024; i += 256) {
        u32 x = w[i];
        m = max(m, max((int)((x >> 7) & 0xFF), (int)((x >> 23) & 0xFF)));
    }
    smax[tid] = m;
    __syncthreads();
    if (tid == 0) {
        int mm = 0;
        for (int i = 0; i < 256; ++i) mm = max(mm, smax[i]);
        *flag = (mm >= 200) ? 1 : 0;
    }
}

// ---------------------------------------------------------------------------
// Kernel 0b: W -> Wt, bf16, transposed + tiled for MFMA B-fragment reads.
// ---------------------------------------------------------------------------
__global__ __launch_bounds__(256) void prep_w_kernel(
    const void* __restrict__ Wq, const void* __restrict__ Wk, const void* __restrict__ Wv,
    u16* __restrict__ Wt, const int* __restrict__ dflag)
{
    const int kt = blockIdx.x, mat = blockIdx.y;
    const void* W = (mat == 0) ? Wq : (mat == 1) ? Wk : Wv;
    const int isf = *dflag;
    const int t = threadIdx.x;
    const int kk = t >> 3;            // 0..31 (k within tile)
    const int n0 = (t & 7) * 16;      // 16 n per thread
    u16 vals[16];
    if (isf) {
        const float* wp = (const float*)W + (size_t)(kt * 32 + kk) * H_ + n0;
#pragma unroll
        for (int i = 0; i < 16; ++i) vals[i] = f2bf(wp[i]);
    } else {
        const u16* wp = (const u16*)W + (size_t)(kt * 32 + kk) * H_ + n0;
#pragma unroll
        for (int i = 0; i < 16; ++i) vals[i] = wp[i];
    }
    const size_t base = (size_t)(mat * 32 + kt) * 128;
#pragma unroll
    for (int i = 0; i < 16; ++i)
        Wt[(base + n0 + i) * 32 + kk] = vals[i];
}

// ---------------------------------------------------------------------------
// Kernel 1: fused QKV GEMM via MFMA 16x16x32 bf16.
// Q pre-scaled by 1/sqrt(128). Q,K row-major bf16; V stored TRANSPOSED
// (Vt[b][h][s]) so the attention kernel never transposes in LDS (round-4
// bank-conflict post-mortem: in-attn transpose was 32-way conflicted).
// ---------------------------------------------------------------------------
__global__ __launch_bounds__(256) void qkv_kernel(
    const void* __restrict__ Xv, const u16* __restrict__ Wt,
    u16* __restrict__ Qo, u16* __restrict__ Ko, u16* __restrict__ Vto,
    const int* __restrict__ dflag)
{
    __shared__ u16 Xs[64 * 40];     // 64 rows x 32 k, stride 40
    __shared__ u16 Ws[384 * 40];    // 3*128 n-rows x 32 k, stride 40
    __shared__ union {
        u16 qk[64 * 136];           // row-major bounce for Q,K
        u16 vt[128 * 72];           // transposed bounce for V (h-major)
    } OsU;

    const int isf = *dflag;
    const int tid = threadIdx.x;
    const int w = tid >> 6, lane = tid & 63;
    const int r = lane & 15, q = lane >> 4;
    const size_t m0 = (size_t)blockIdx.x * 64;

    f32x4 acc[3][8];
#pragma unroll
    for (int m = 0; m < 3; ++m)
#pragma unroll
        for (int nt = 0; nt < 8; ++nt) acc[m][nt] = (f32x4){0.f, 0.f, 0.f, 0.f};

    const int xr = tid >> 2, xo = tid & 3;   // X stage: row, k-octet

    for (int kt = 0; kt < 32; ++kt) {
        const int k0 = kt * 32;
        if (isf) {
            const float* xp = (const float*)Xv + (m0 + xr) * D_ + k0 + xo * 8;
            float4 a = *(const float4*)xp, b2 = *(const float4*)(xp + 4);
            union { u16 u[8]; uint4 v; } pk;
            pk.u[0] = f2bf(a.x);  pk.u[1] = f2bf(a.y);
            pk.u[2] = f2bf(a.z);  pk.u[3] = f2bf(a.w);
            pk.u[4] = f2bf(b2.x); pk.u[5] = f2bf(b2.y);
            pk.u[6] = f2bf(b2.z); pk.u[7] = f2bf(b2.w);
            *(uint4*)&Xs[xr * 40 + xo * 8] = pk.v;
        } else {
            *(uint4*)&Xs[xr * 40 + xo * 8] =
                *(const uint4*)((const u16*)Xv + (m0 + xr) * D_ + k0 + xo * 8);
        }
#pragma unroll
        for (int i = 0; i < 6; ++i) {
            int c = tid + i * 256;              // 1536 16B chunks
            int row = c >> 2, part = c & 3;     // row 0..383
            int mat = row >> 7, nn = row & 127;
            *(uint4*)&Ws[row * 40 + part * 8] =
                *(const uint4*)(Wt + ((size_t)(mat * 32 + kt) * 128 + nn) * 32 + part * 8);
        }
        __syncthreads();

        s16x8 a = *(const s16x8*)&Xs[(w * 16 + r) * 40 + q * 8];
#pragma unroll
        for (int m = 0; m < 3; ++m)
#pragma unroll
            for (int nt = 0; nt < 8; ++nt) {
                s16x8 b = *(const s16x8*)&Ws[(m * 128 + nt * 16 + r) * 40 + q * 8];
                acc[m][nt] = __builtin_amdgcn_mfma_f32_16x16x32_bf16(a, b, acc[m][nt], 0, 0, 0);
            }
        __syncthreads();
    }

    // ---- epilogue: Q and K row-major ----
    u16* outs[2] = {Qo, Ko};
    for (int m = 0; m < 2; ++m) {
        const float sc = (m == 0) ? 0.08838834764831845f : 1.0f;
#pragma unroll
        for (int nt = 0; nt < 8; ++nt)
#pragma unroll
            for (int reg = 0; reg < 4; ++reg)
                OsU.qk[(w * 16 + q * 4 + reg) * 136 + nt * 16 + r] = f2bf(acc[m][nt][reg] * sc);
        __syncthreads();
        u16* Out = outs[m];
#pragma unroll
        for (int i = 0; i < 4; ++i) {
            int c = tid + i * 256;
            int row = c >> 4, col = (c & 15) * 8;
            *(uint4*)(Out + (m0 + row) * H_ + col) = *(const uint4*)&OsU.qk[row * 136 + col];
        }
        __syncthreads();
    }

    // ---- V transposed: OsU.vt[h][s_local], then Vt[b][h][s] global ----
#pragma unroll
    for (int nt = 0; nt < 8; ++nt)
#pragma unroll
        for (int reg = 0; reg < 4; ++reg)
            OsU.vt[(nt * 16 + r) * 72 + (w * 16 + q * 4 + reg)] = f2bf(acc[2][nt][reg]);
    __syncthreads();
    {
        const int bb = blockIdx.x >> 6;          // batch of this row-tile
        const int s0 = (blockIdx.x & 63) * 64;   // s offset within batch
        const int h = tid >> 1, sh = (tid & 1) * 32;
        const u16* src = &OsU.vt[h * 72 + sh];
        u16* dst = Vto + ((size_t)bb * H_ + h) * S_ + s0 + sh;
#pragma unroll
        for (int i = 0; i < 4; ++i)
            *(uint4*)(dst + i * 8) = *(const uint4*)(src + i * 8);
    }
}

// ---------------------------------------------------------------------------
// Kernel 2: causal flash attention via MFMA. QT=32, KT=64.
// grid (64, 4): block p handles q-tiles {p, 127-p} -> constant 65 K-tiles.
// V arrives pre-transposed (Vt[b][h][s]) -> straight uint4 staging.
// K/V tiles register-prefetched one iteration ahead.
// ---------------------------------------------------------------------------
__global__ __launch_bounds__(256) void attn_kernel(
    const u16* __restrict__ Q, const u16* __restrict__ K, const u16* __restrict__ Vt,
    void* __restrict__ out, const int* __restrict__ dflag)
{
    __shared__ u16 Qs[32 * 136];
    __shared__ union { u16 ks[64 * 136]; float of[32 * 132]; } KU;  // K tile / O bounce
    __shared__ u16 Vts[128 * 72];   // [h][k] tile
    __shared__ float Sf[32 * 68];
    __shared__ u16 Ps[32 * 72];
    __shared__ float mrow[32], lrow[32], arow[32];

    const int isf = *dflag;
    const int tid = threadIdx.x;
    const int w = tid >> 6, lane = tid & 63;
    const int r = lane & 15, q = lane >> 4;
    const int b = blockIdx.y;
    const int mw = w & 1;            // S/O row-tile of this wave
    const int nb = (w >> 1) * 2;     // S key-tile pair
    const int hb = (w >> 1) * 4;     // O h-tile quad
    const int srow = tid >> 3, sseg = tid & 7;   // softmax map: 8 threads/row

    const u16* Kg  = K  + (size_t)b * S_ * H_;
    const u16* Vtg = Vt + (size_t)b * H_ * S_;

    for (int pass = 0; pass < 2; ++pass) {
        const int qt = pass ? (127 - blockIdx.x) : blockIdx.x;
        const u16* Qg = Q + ((size_t)b * S_ + (size_t)qt * 32) * H_;
#pragma unroll
        for (int i = 0; i < 2; ++i) {
            int c = tid + i * 256;
            int row = c >> 4, col = (c & 15) * 8;
            *(uint4*)&Qs[row * 136 + col] = *(const uint4*)(Qg + (size_t)row * H_ + col);
        }
        if (tid < 32) { mrow[tid] = -1e30f; lrow[tid] = 0.f; }

        f32x4 accO[4];
#pragma unroll
        for (int ht = 0; ht < 4; ++ht) accO[ht] = (f32x4){0.f, 0.f, 0.f, 0.f};

        const int nKT = (qt + 2) >> 1;

        // prefetch tile 0 into registers
        uint4 kp[4], vp[4];
#pragma unroll
        for (int i = 0; i < 4; ++i) {
            int c = tid + i * 256;
            kp[i] = *(const uint4*)(Kg + ((size_t)(c >> 4)) * H_ + (c & 15) * 8);
            vp[i] = *(const uint4*)(Vtg + (size_t)(c >> 3) * S_ + (c & 7) * 8);
        }

        for (int j = 0; j < nKT; ++j) {
            __syncthreads();   // prev iter done with KU.ks/Vts; Qs/state ready (j==0)
#pragma unroll
            for (int i = 0; i < 4; ++i) {
                int c = tid + i * 256;
                *(uint4*)&KU.ks[(c >> 4) * 136 + (c & 15) * 8] = kp[i];
                *(uint4*)&Vts[(c >> 3) * 72 + (c & 7) * 8] = vp[i];
            }
            __syncthreads();

            if (j + 1 < nKT) {   // prefetch next tile; latency overlaps compute
#pragma unroll
                for (int i = 0; i < 4; ++i) {
                    int c = tid + i * 256;
                    kp[i] = *(const uint4*)(Kg + ((size_t)(j + 1) * 64 + (c >> 4)) * H_ + (c & 15) * 8);
                    vp[i] = *(const uint4*)(Vtg + (size_t)(c >> 3) * S_ + (size_t)(j + 1) * 64 + (c & 7) * 8);
                }
            }

            // ---- S = Q K^T (Q pre-scaled) ----
            f32x4 accS[2];
            accS[0] = (f32x4){0.f, 0.f, 0.f, 0.f};
            accS[1] = (f32x4){0.f, 0.f, 0.f, 0.f};
#pragma unroll
            for (int ks = 0; ks < 4; ++ks) {
                s16x8 a = *(const s16x8*)&Qs[(mw * 16 + r) * 136 + ks * 32 + q * 8];
#pragma unroll
                for (int t2 = 0; t2 < 2; ++t2) {
                    s16x8 bb = *(const s16x8*)&KU.ks[((nb + t2) * 16 + r) * 136 + ks * 32 + q * 8];
                    accS[t2] = __builtin_amdgcn_mfma_f32_16x16x32_bf16(a, bb, accS[t2], 0, 0, 0);
                }
            }
#pragma unroll
            for (int t2 = 0; t2 < 2; ++t2)
#pragma unroll
                for (int reg = 0; reg < 4; ++reg)
                    Sf[(mw * 16 + q * 4 + reg) * 68 + (nb + t2) * 16 + r] = accS[t2][reg];
            __syncthreads();

            // ---- online softmax (8 threads per row, wave-synchronous) ----
            {
                float4 s0 = *(const float4*)&Sf[srow * 68 + sseg * 8];
                float4 s1 = *(const float4*)&Sf[srow * 68 + sseg * 8 + 4];
                float sv[8] = {s0.x, s0.y, s0.z, s0.w, s1.x, s1.y, s1.z, s1.w};
                if (j == nKT - 1) {   // only the last tile can cross the diagonal
                    int grow = qt * 32 + srow;
#pragma unroll
                    for (int i = 0; i < 8; ++i)
                        if (j * 64 + sseg * 8 + i > grow) sv[i] = -1e30f;
                }
                float m8 = sv[0];
#pragma unroll
                for (int i = 1; i < 8; ++i) m8 = fmaxf(m8, sv[i]);
                m8 = fmaxf(m8, __shfl_xor(m8, 1));
                m8 = fmaxf(m8, __shfl_xor(m8, 2));
                m8 = fmaxf(m8, __shfl_xor(m8, 4));
                float mold = mrow[srow];
                float mnew = fmaxf(mold, m8);
                float psum = 0.f;
                union { u16 u[8]; uint4 v; } pk;
#pragma unroll
                for (int i = 0; i < 8; ++i) {
                    float p = __expf(sv[i] - mnew);
                    psum += p;
                    pk.u[i] = f2bf(p);
                }
                *(uint4*)&Ps[srow * 72 + sseg * 8] = pk.v;
                psum += __shfl_xor(psum, 1);
                psum += __shfl_xor(psum, 2);
                psum += __shfl_xor(psum, 4);
                if (sseg == 0) {
                    float alpha = __expf(mold - mnew);
                    mrow[srow] = mnew;
                    arow[srow] = alpha;
                    lrow[srow] = lrow[srow] * alpha + psum;
                }
            }
            __syncthreads();

            // ---- O = O*alpha + P V ----
            float alr[4];
#pragma unroll
            for (int reg = 0; reg < 4; ++reg) alr[reg] = arow[mw * 16 + q * 4 + reg];
#pragma unroll
            for (int ht = 0; ht < 4; ++ht)
#pragma unroll
                for (int reg = 0; reg < 4; ++reg) accO[ht][reg] *= alr[reg];
#pragma unroll
            for (int ks = 0; ks < 2; ++ks) {
                s16x8 a = *(const s16x8*)&Ps[(mw * 16 + r) * 72 + ks * 32 + q * 8];
#pragma unroll
                for (int ht = 0; ht < 4; ++ht) {
                    s16x8 bb = *(const s16x8*)&Vts[((hb + ht) * 16 + r) * 72 + ks * 32 + q * 8];
                    accO[ht] = __builtin_amdgcn_mfma_f32_16x16x32_bf16(a, bb, accO[ht], 0, 0, 0);
                }
            }
        }

        // ---- epilogue: normalize, bounce via LDS, coalesced store ----
        float linv[4];
#pragma unroll
        for (int reg = 0; reg < 4; ++reg) linv[reg] = 1.0f / lrow[mw * 16 + q * 4 + reg];
#pragma unroll
        for (int ht = 0; ht < 4; ++ht)
#pragma unroll
            for (int reg = 0; reg < 4; ++reg)
                KU.of[(mw * 16 + q * 4 + reg) * 132 + (hb + ht) * 16 + r] = accO[ht][reg] * linv[reg];
        __syncthreads();
        {
            const size_t obase = (size_t)b * S_ + (size_t)qt * 32;
            int row = tid >> 3, col = (tid & 7) * 16;
            const float* src = &KU.of[row * 132 + col];
            if (isf) {
                float* dst = (float*)out + (obase + row) * H_ + col;
#pragma unroll
                for (int i = 0; i < 4; ++i)
                    *(float4*)(dst + i * 4) = *(const float4*)(src + i * 4);
            } else {
                u16* dst = (u16*)out + (obase + row) * H_ + col;
#pragma unroll
                for (int hh = 0; hh < 2; ++hh) {
                    union { u16 u[8]; uint4 v; } pk;
#pragma unroll
                    for (int i = 0; i < 8; ++i) pk.u[i] = f2bf(src[hh * 8 + i]);
                    *(uint4*)(dst + hh * 8) = pk.v;
                }
            }
        }
        __syncthreads();   // protect KU/Qs/state before next pass restage
    }
}

extern "C" void kernel_launch(void* const* d_in, const int* in_sizes, int n_in,
                              void* d_out, int out_size, void* d_ws, size_t ws_size,
                              hipStream_t stream) {
    (void)in_sizes; (void)n_in; (void)out_size; (void)ws_size;
    const void* X  = d_in[0];
    const void* Wq = d_in[1];
    const void* Wk = d_in[2];
    const void* Wv = d_in[3];

    int* dflag = (int*)d_ws;                          // 256 B header
    u16* Qw = (u16*)((char*)d_ws + 256);
    const size_t n = (size_t)B_ * S_ * H_;            // 2M elems per tensor
    u16* Kw = Qw + n;
    u16* Vtw = Kw + n;                                // V stored transposed [b][h][s]
    u16* Wt = Vtw + n;                                // 3*1024*128 bf16 = 768 KB

    detect_dtype_kernel<<<1, 256, 0, stream>>>((const u32*)Wq, dflag);
    prep_w_kernel<<<dim3(32, 3), 256, 0, stream>>>(Wq, Wk, Wv, Wt, dflag);
    qkv_kernel<<<256, 256, 0, stream>>>(X, Wt, Qw, Kw, Vtw, dflag);
    attn_kernel<<<dim3(64, B_), 256, 0, stream>>>(Qw, Kw, Vtw, d_out, dflag);
}